// Round 4
// baseline (799.060 us; speedup 1.0000x reference)
//
#include <hip/hip_runtime.h>
#include <hip/hip_bf16.h>
#include <math.h>

// Problem constants: B=1, S=2048, DIM=4096, NH=32, NKV=8, HD=128
// qkv width = (32+2*8)*128 = 6144; q cols [0,4096), k cols [4096,5120), v cols [5120,6144)
//
// ROUND 4: dtype fix. d_in/d_out are FLOAT32 (round-3 absmax 30086.47 =
// 30080+6.47 proves fp32 readback of bf16-half words; garbage-triggered
// clamps prove fp32 inputs). Convert fp32->bf16 inline during LDS staging;
// internal workspaces bf16; final GEMM stores fp32. Clamps kept as tripwires.

typedef __attribute__((ext_vector_type(8))) __bf16 bf16x8;
typedef __attribute__((ext_vector_type(4))) float f32x4;

#define NEG_BIG (-1e30f)

__device__ __forceinline__ f32x4 mfma_bf16(bf16x8 a, bf16x8 b, f32x4 c) {
  return __builtin_amdgcn_mfma_f32_16x16x32_bf16(a, b, c, 0, 0, 0);
}

// fmaxf(NaN, a) = a on AMD (IEEE maxNum) -> clamp also converts NaN to -3e4.
__device__ __forceinline__ float clampf(float v) {
  return fminf(fmaxf(v, -30000.f), 30000.f);
}

// load 8 consecutive elements as bf16x8, converting if source is fp32
__device__ __forceinline__ bf16x8 ldg8(const __hip_bfloat16* p) {
  return *(const bf16x8*)p;
}
__device__ __forceinline__ bf16x8 ldg8(const float* p) {
  f32x4 a = *(const f32x4*)p;
  f32x4 b = *(const f32x4*)(p + 4);
  bf16x8 r;
  r[0] = (__bf16)a[0]; r[1] = (__bf16)a[1]; r[2] = (__bf16)a[2]; r[3] = (__bf16)a[3];
  r[4] = (__bf16)b[0]; r[5] = (__bf16)b[1]; r[6] = (__bf16)b[2]; r[7] = (__bf16)b[3];
  return r;
}

__device__ __forceinline__ void store_c(float* C, size_t idx, float v) {
  C[idx] = clampf(v);
}
__device__ __forceinline__ void store_c(__hip_bfloat16* C, size_t idx, float v) {
  C[idx] = __float2bfloat16(clampf(v));
}

// ---------------------------------------------------------------------------
// NT GEMM: C[M,N] = A[M,K] * B[N,K]^T; A/B fp32 or bf16 (inline cvt), fp32
// accum; C fp32 or bf16. 128x128 tile, BK=32, 4 waves each 64x64.
// ---------------------------------------------------------------------------
template <typename TA, typename TB, typename TC>
__global__ __launch_bounds__(256) void gemm_nt(
    const TA* __restrict__ A, const TB* __restrict__ B,
    TC* __restrict__ C, int M, int N, int K) {
  __shared__ __align__(16) __hip_bfloat16 As[128 * 32];
  __shared__ __align__(16) __hip_bfloat16 Bs[128 * 32];
  const int tid = threadIdx.x;
  const int lane = tid & 63;
  const int wave = tid >> 6;
  const int l15 = lane & 15, quad = lane >> 4;
  const int wm = (wave >> 1) * 64, wn = (wave & 1) * 64;
  const size_t mBase = (size_t)blockIdx.y * 128, nBase = (size_t)blockIdx.x * 128;

  const int ldRow = tid >> 2;        // 0..63
  const int ldCol = (tid & 3) * 8;   // 0,8,16,24
  const TA* Ap = A + (mBase + ldRow) * (size_t)K + ldCol;
  const TB* Bp = B + (nBase + ldRow) * (size_t)K + ldCol;

  f32x4 acc[4][4] = {};

  for (int k0 = 0; k0 < K; k0 += 32) {
    bf16x8 a0 = ldg8(Ap);
    bf16x8 a1 = ldg8(Ap + (size_t)64 * K);
    bf16x8 b0 = ldg8(Bp);
    bf16x8 b1 = ldg8(Bp + (size_t)64 * K);
    Ap += 32; Bp += 32;
    *(bf16x8*)&As[tid * 8] = a0;          // row tid>>2, col (tid&3)*8
    *(bf16x8*)&As[2048 + tid * 8] = a1;   // rows 64..127
    *(bf16x8*)&Bs[tid * 8] = b0;
    *(bf16x8*)&Bs[2048 + tid * 8] = b1;
    __syncthreads();
    bf16x8 af[4], bfr[4];
#pragma unroll
    for (int i = 0; i < 4; i++)
      af[i] = *(const bf16x8*)&As[(wm + i * 16 + l15) * 32 + quad * 8];
#pragma unroll
    for (int j = 0; j < 4; j++)
      bfr[j] = *(const bf16x8*)&Bs[(wn + j * 16 + l15) * 32 + quad * 8];
#pragma unroll
    for (int i = 0; i < 4; i++)
#pragma unroll
      for (int j = 0; j < 4; j++)
        acc[i][j] = mfma_bf16(af[i], bfr[j], acc[i][j]);
    __syncthreads();
  }

#pragma unroll
  for (int i = 0; i < 4; i++)
#pragma unroll
    for (int j = 0; j < 4; j++)
#pragma unroll
      for (int r = 0; r < 4; r++) {
        size_t row = mBase + wm + i * 16 + quad * 4 + r;  // C/D: row=(lane>>4)*4+r
        size_t col = nBase + wn + j * 16 + l15;           //      col=lane&15
        store_c(C, row * (size_t)N + col, acc[i][j][r]);
      }
}

// ---------------------------------------------------------------------------
// RoPE in-place on q (heads 0..31) and k (heads 32..39) of qkv[2048][6144]
// (bf16). freqs_cis read directly as fp32 [2048][64][2].
// ---------------------------------------------------------------------------
__global__ __launch_bounds__(256) void rope_kernel(__hip_bfloat16* __restrict__ qkv,
                                                   const float* __restrict__ fc) {
  int idx = blockIdx.x * 256 + threadIdx.x;  // 2048*40*64 total
  int d = idx & 63;
  int h = (idx >> 6) % 40;
  int s = idx / (40 * 64);
  size_t off = (size_t)s * 6144 + h * 128 + d * 2;  // h*128 works for k too (32*128=4096)
  float x0 = __bfloat162float(qkv[off]);
  float x1 = __bfloat162float(qkv[off + 1]);
  float c = fc[s * 128 + d * 2];
  float sn = fc[s * 128 + d * 2 + 1];
  qkv[off] = __float2bfloat16(x0 * c - x1 * sn);
  qkv[off + 1] = __float2bfloat16(x0 * sn + x1 * c);
}

// ---------------------------------------------------------------------------
// V transpose: vt[g*128+n][s] = qkv[s][5120 + g*128 + n].  (1024 rows x 2048)
// ---------------------------------------------------------------------------
__global__ __launch_bounds__(256) void transpose_v(const __hip_bfloat16* __restrict__ qkv,
                                                   __hip_bfloat16* __restrict__ vt) {
  __shared__ __hip_bfloat16 tile[32][33];
  int x = threadIdx.x & 31, y = threadIdx.x >> 5;  // y: 0..7
  int colBase = blockIdx.x * 32;  // 0..1023
  int sBase = blockIdx.y * 32;
#pragma unroll
  for (int i = 0; i < 4; i++)
    tile[y + i * 8][x] = qkv[(size_t)(sBase + y + i * 8) * 6144 + 5120 + colBase + x];
  __syncthreads();
#pragma unroll
  for (int i = 0; i < 4; i++)
    vt[(size_t)(colBase + y + i * 8) * 2048 + sBase + x] = tile[x][y + i * 8];
}

// ---------------------------------------------------------------------------
// Flash attention, causal GQA. grid = (S/64, NH). 4 waves x 16 q-rows.
// Plain (unswizzled) K/Vt staging through registers. P round-trips through
// LDS (stride 72) from C-layout to A-layout, barrier-guarded.
// ---------------------------------------------------------------------------
__global__ __launch_bounds__(256) void flash_attn(
    const __hip_bfloat16* __restrict__ qkv, const __hip_bfloat16* __restrict__ vt,
    __hip_bfloat16* __restrict__ o) {
  __shared__ __align__(16) __hip_bfloat16 Ks[64 * 128];
  __shared__ __align__(16) __hip_bfloat16 Vs[128 * 64];
  __shared__ __align__(16) __hip_bfloat16 Ps[4][16 * 72];
  const int tid = threadIdx.x;
  const int lane = tid & 63, wave = tid >> 6;
  const int l15 = lane & 15, quad = lane >> 4;
  const int h = blockIdx.y, g = h >> 2;  // GQA: kv head = h/4
  const int qBase = blockIdx.x * 64;
  const int qRow = qBase + wave * 16;

  bf16x8 qf[4];
  {
    const __hip_bfloat16* qp = qkv + (size_t)(qRow + l15) * 6144 + h * 128 + quad * 8;
#pragma unroll
    for (int d = 0; d < 4; d++) qf[d] = *(const bf16x8*)(qp + d * 32);
  }

  f32x4 acc_o[8] = {};
  float m_i[4], l_i[4];
#pragma unroll
  for (int r = 0; r < 4; r++) { m_i[r] = NEG_BIG; l_i[r] = 0.f; }

  const float scale = 0.08838834764831845f;  // 1/sqrt(128)
  const int nkt = blockIdx.x + 1;
  for (int kt = 0; kt < nkt; kt++) {
    const int kBase = kt * 64;
    // stage K tile [64][128]: 1024 16B-chunks, 4 per thread
#pragma unroll
    for (int rnd = 0; rnd < 4; rnd++) {
      int ci = rnd * 256 + tid;
      int row = ci >> 4, ch = ci & 15;
      bf16x8 kv = *(const bf16x8*)(qkv + (size_t)(kBase + row) * 6144 + 4096 + g * 128 + ch * 8);
      *(bf16x8*)&Ks[ci * 8] = kv;
    }
    // stage Vt tile [128][64]: 1024 16B-chunks
#pragma unroll
    for (int rnd = 0; rnd < 4; rnd++) {
      int ci = rnd * 256 + tid;
      int n = ci >> 3, ch = ci & 7;
      bf16x8 vv = *(const bf16x8*)(vt + (size_t)(g * 128 + n) * 2048 + kBase + ch * 8);
      *(bf16x8*)&Vs[ci * 8] = vv;
    }
    __syncthreads();

    // S = Q K^T : 4 d-steps x 4 k-col tiles
    f32x4 sc[4] = {};
#pragma unroll
    for (int d = 0; d < 4; d++) {
#pragma unroll
      for (int j = 0; j < 4; j++) {
        bf16x8 kb = *(const bf16x8*)&Ks[(j * 16 + l15) * 128 + (d * 4 + quad) * 8];
        sc[j] = mfma_bf16(qf[d], kb, sc[j]);
      }
    }

    // scale + causal mask + online softmax (rows = quad*4+r over 16 lanes)
    float rowmax[4] = {NEG_BIG, NEG_BIG, NEG_BIG, NEG_BIG};
    float sv[4][4];
#pragma unroll
    for (int j = 0; j < 4; j++) {
      int kcol = kBase + j * 16 + l15;
#pragma unroll
      for (int r = 0; r < 4; r++) {
        float s = clampf(sc[j][r] * scale);  // tripwire: garbage can't become inf
        if (kcol > qRow + quad * 4 + r) s = NEG_BIG;
        sv[j][r] = s;
        rowmax[r] = fmaxf(rowmax[r], s);
      }
    }
#pragma unroll
    for (int off = 8; off; off >>= 1)
#pragma unroll
      for (int r = 0; r < 4; r++)
        rowmax[r] = fmaxf(rowmax[r], __shfl_xor(rowmax[r], off, 16));

    float alpha[4], rowsum[4];
#pragma unroll
    for (int r = 0; r < 4; r++) {
      float mnew = fmaxf(m_i[r], rowmax[r]);
      alpha[r] = __expf(m_i[r] - mnew);  // first tile: exp(-1e30) == 0
      m_i[r] = mnew;
      rowsum[r] = 0.f;
    }
#pragma unroll
    for (int j = 0; j < 4; j++)
#pragma unroll
      for (int r = 0; r < 4; r++) {
        float p = __expf(sv[j][r] - m_i[r]);  // arg <= 0 always
        rowsum[r] += p;
        Ps[wave][(quad * 4 + r) * 72 + j * 16 + l15] = __float2bfloat16(p);
      }
#pragma unroll
    for (int off = 8; off; off >>= 1)
#pragma unroll
      for (int r = 0; r < 4; r++)
        rowsum[r] += __shfl_xor(rowsum[r], off, 16);
#pragma unroll
    for (int r = 0; r < 4; r++) l_i[r] = l_i[r] * alpha[r] + rowsum[r];

#pragma unroll
    for (int jt = 0; jt < 8; jt++)
#pragma unroll
      for (int r = 0; r < 4; r++) acc_o[jt][r] *= alpha[r];

    __syncthreads();  // P write (C-layout) -> P read (A-layout)

    // O += P V
#pragma unroll
    for (int kk = 0; kk < 2; kk++) {
      bf16x8 pa = *(const bf16x8*)&Ps[wave][l15 * 72 + kk * 32 + quad * 8];
#pragma unroll
      for (int jt = 0; jt < 8; jt++) {
        bf16x8 vb = *(const bf16x8*)&Vs[(jt * 16 + l15) * 64 + (kk * 4 + quad) * 8];
        acc_o[jt] = mfma_bf16(pa, vb, acc_o[jt]);
      }
    }
    __syncthreads();
  }

#pragma unroll
  for (int r = 0; r < 4; r++) {
    float inv = 1.f / l_i[r];  // l_i >= 1 always
    size_t qr = qRow + quad * 4 + r;
#pragma unroll
    for (int jt = 0; jt < 8; jt++)
      o[qr * 4096 + h * 128 + jt * 16 + l15] = __float2bfloat16(clampf(acc_o[jt][r] * inv));
  }
}

// ---------------------------------------------------------------------------
extern "C" void kernel_launch(void* const* d_in, const int* in_sizes, int n_in,
                              void* d_out, int out_size, void* d_ws, size_t ws_size,
                              hipStream_t stream) {
  const float* x = (const float*)d_in[0];     // [2048][4096] fp32
  const float* fc = (const float*)d_in[1];    // [2048][64][2] fp32
  const float* wqkv = (const float*)d_in[2];  // [6144][4096] fp32
  const float* wo = (const float*)d_in[3];    // [4096][4096] fp32
  float* out = (float*)d_out;                 // [2048][4096] fp32

  char* ws = (char*)d_ws;
  __hip_bfloat16* qkv = (__hip_bfloat16*)ws;                          // 25,165,824 B
  __hip_bfloat16* vt = (__hip_bfloat16*)(ws + 25165824);              //  4,194,304 B
  __hip_bfloat16* ob = (__hip_bfloat16*)(ws + 25165824 + 4194304);    // 16,777,216 B

  // qkv = bf16(x) @ bf16(wqkv)^T  (inline cvt during staging)
  gemm_nt<float, float, __hip_bfloat16>
      <<<dim3(48, 16), 256, 0, stream>>>(x, wqkv, qkv, 2048, 6144, 4096);
  rope_kernel<<<dim3(20480), 256, 0, stream>>>(qkv, fc);
  transpose_v<<<dim3(32, 64), 256, 0, stream>>>(qkv, vt);
  flash_attn<<<dim3(32, 32), 256, 0, stream>>>(qkv, vt, ob);
  // out = ob @ bf16(wo)^T, fp32 store
  gemm_nt<__hip_bfloat16, float, float>
      <<<dim3(32, 16), 256, 0, stream>>>(ob, wo, out, 2048, 4096, 4096);
}

// Round 5
// 633.981 us; speedup vs baseline: 1.2604x; 1.2604x over previous
//
#include <hip/hip_runtime.h>
#include <hip/hip_bf16.h>
#include <math.h>

// Problem constants: B=1, S=2048, DIM=4096, NH=32, NKV=8, HD=128
// qkv width = (32+2*8)*128 = 6144; q cols [0,4096), k cols [4096,5120), v cols [5120,6144)
//
// ROUND 5: (a) flash_attn: XOR-chunk-swizzled K/V LDS (kills the 4.4e7
// bank-conflict cycles; post-swizzle reads are 2-way = free per m136) +
// global_load_lds staging. (b) GEMMs: pre-convert fp32->bf16 (~50us BW) and
// run the m97 874TF structure with async staging; ws_size-gated with the
// round-4 register-staging GEMM as fallback (ws >= 46MB proven only).

typedef __attribute__((ext_vector_type(8))) __bf16 bf16x8;
typedef __attribute__((ext_vector_type(4))) float f32x4;

#define NEG_BIG (-1e30f)

#define ASYNC_CP16(gsrc, ldst)                                                            \
  __builtin_amdgcn_global_load_lds((const __attribute__((address_space(1))) void*)(gsrc), \
                                   (__attribute__((address_space(3))) void*)(ldst), 16, 0, 0)

__device__ __forceinline__ f32x4 mfma_bf16(bf16x8 a, bf16x8 b, f32x4 c) {
  return __builtin_amdgcn_mfma_f32_16x16x32_bf16(a, b, c, 0, 0, 0);
}

// fmaxf(NaN, a) = a on AMD (IEEE maxNum) -> clamp also converts NaN to -3e4.
__device__ __forceinline__ float clampf(float v) {
  return fminf(fmaxf(v, -30000.f), 30000.f);
}

__device__ __forceinline__ bf16x8 ldg8(const __hip_bfloat16* p) {
  return *(const bf16x8*)p;
}
__device__ __forceinline__ bf16x8 ldg8(const float* p) {
  f32x4 a = *(const f32x4*)p;
  f32x4 b = *(const f32x4*)(p + 4);
  bf16x8 r;
  r[0] = (__bf16)a[0]; r[1] = (__bf16)a[1]; r[2] = (__bf16)a[2]; r[3] = (__bf16)a[3];
  r[4] = (__bf16)b[0]; r[5] = (__bf16)b[1]; r[6] = (__bf16)b[2]; r[7] = (__bf16)b[3];
  return r;
}

__device__ __forceinline__ void store_c(float* C, size_t idx, float v) {
  C[idx] = clampf(v);
}
__device__ __forceinline__ void store_c(__hip_bfloat16* C, size_t idx, float v) {
  C[idx] = __float2bfloat16(clampf(v));
}

// ---------------------------------------------------------------------------
// fp32 -> bf16 bulk convert. n must be a multiple of 2048; 8 elems/thread.
// ---------------------------------------------------------------------------
__global__ __launch_bounds__(256) void cvt_f32_bf16(const float* __restrict__ src,
                                                    __hip_bfloat16* __restrict__ dst) {
  size_t i = ((size_t)blockIdx.x * 256 + threadIdx.x) * 8;
  *(bf16x8*)&dst[i] = ldg8(src + i);
}

// ---------------------------------------------------------------------------
// NT GEMM, register staging (fallback path): C[M,N] = A[M,K]*B[N,K]^T.
// A/B fp32 or bf16 (inline cvt), fp32 accum; C fp32 or bf16.
// ---------------------------------------------------------------------------
template <typename TA, typename TB, typename TC>
__global__ __launch_bounds__(256) void gemm_nt(
    const TA* __restrict__ A, const TB* __restrict__ B,
    TC* __restrict__ C, int M, int N, int K) {
  __shared__ __align__(16) __hip_bfloat16 As[128 * 32];
  __shared__ __align__(16) __hip_bfloat16 Bs[128 * 32];
  const int tid = threadIdx.x;
  const int lane = tid & 63, wave = tid >> 6;
  const int l15 = lane & 15, quad = lane >> 4;
  const int wm = (wave >> 1) * 64, wn = (wave & 1) * 64;
  const size_t mBase = (size_t)blockIdx.y * 128, nBase = (size_t)blockIdx.x * 128;

  const int ldRow = tid >> 2;
  const int ldCol = (tid & 3) * 8;
  const TA* Ap = A + (mBase + ldRow) * (size_t)K + ldCol;
  const TB* Bp = B + (nBase + ldRow) * (size_t)K + ldCol;

  f32x4 acc[4][4] = {};

  for (int k0 = 0; k0 < K; k0 += 32) {
    bf16x8 a0 = ldg8(Ap);
    bf16x8 a1 = ldg8(Ap + (size_t)64 * K);
    bf16x8 b0 = ldg8(Bp);
    bf16x8 b1 = ldg8(Bp + (size_t)64 * K);
    Ap += 32; Bp += 32;
    *(bf16x8*)&As[tid * 8] = a0;
    *(bf16x8*)&As[2048 + tid * 8] = a1;
    *(bf16x8*)&Bs[tid * 8] = b0;
    *(bf16x8*)&Bs[2048 + tid * 8] = b1;
    __syncthreads();
    bf16x8 af[4], bfr[4];
#pragma unroll
    for (int i = 0; i < 4; i++)
      af[i] = *(const bf16x8*)&As[(wm + i * 16 + l15) * 32 + quad * 8];
#pragma unroll
    for (int j = 0; j < 4; j++)
      bfr[j] = *(const bf16x8*)&Bs[(wn + j * 16 + l15) * 32 + quad * 8];
#pragma unroll
    for (int i = 0; i < 4; i++)
#pragma unroll
      for (int j = 0; j < 4; j++)
        acc[i][j] = mfma_bf16(af[i], bfr[j], acc[i][j]);
    __syncthreads();
  }

#pragma unroll
  for (int i = 0; i < 4; i++)
#pragma unroll
    for (int j = 0; j < 4; j++)
#pragma unroll
      for (int r = 0; r < 4; r++) {
        size_t row = mBase + wm + i * 16 + quad * 4 + r;  // C/D: row=(lane>>4)*4+r
        size_t col = nBase + wn + j * 16 + l15;           //      col=lane&15
        store_c(C, row * (size_t)N + col, acc[i][j][r]);
      }
}

// ---------------------------------------------------------------------------
// NT GEMM, m97 structure (fast path): bf16 in via global_load_lds width=16.
// ---------------------------------------------------------------------------
template <typename TC>
__global__ __launch_bounds__(256) void gemm_nt_async(
    const __hip_bfloat16* __restrict__ A, const __hip_bfloat16* __restrict__ B,
    TC* __restrict__ C, int M, int N, int K) {
  __shared__ __align__(16) __hip_bfloat16 As[128 * 32];
  __shared__ __align__(16) __hip_bfloat16 Bs[128 * 32];
  const int tid = threadIdx.x;
  const int lane = tid & 63, wave = tid >> 6;
  const int l15 = lane & 15, quad = lane >> 4;
  const int wm = (wave >> 1) * 64, wn = (wave & 1) * 64;
  const size_t mBase = (size_t)blockIdx.y * 128, nBase = (size_t)blockIdx.x * 128;

  const int ldRow = tid >> 2;
  const int ldCol = (tid & 3) * 8;
  const __hip_bfloat16* Ap = A + (mBase + ldRow) * (size_t)K + ldCol;
  const __hip_bfloat16* Bp = B + (nBase + ldRow) * (size_t)K + ldCol;

  f32x4 acc[4][4] = {};

  for (int k0 = 0; k0 < K; k0 += 32) {
    ASYNC_CP16(Ap, &As[tid * 8]);
    ASYNC_CP16(Ap + (size_t)64 * K, &As[2048 + tid * 8]);
    ASYNC_CP16(Bp, &Bs[tid * 8]);
    ASYNC_CP16(Bp + (size_t)64 * K, &Bs[2048 + tid * 8]);
    Ap += 32; Bp += 32;
    __syncthreads();
    bf16x8 af[4], bfr[4];
#pragma unroll
    for (int i = 0; i < 4; i++)
      af[i] = *(const bf16x8*)&As[(wm + i * 16 + l15) * 32 + quad * 8];
#pragma unroll
    for (int j = 0; j < 4; j++)
      bfr[j] = *(const bf16x8*)&Bs[(wn + j * 16 + l15) * 32 + quad * 8];
#pragma unroll
    for (int i = 0; i < 4; i++)
#pragma unroll
      for (int j = 0; j < 4; j++)
        acc[i][j] = mfma_bf16(af[i], bfr[j], acc[i][j]);
    __syncthreads();
  }

#pragma unroll
  for (int i = 0; i < 4; i++)
#pragma unroll
    for (int j = 0; j < 4; j++)
#pragma unroll
      for (int r = 0; r < 4; r++) {
        size_t row = mBase + wm + i * 16 + quad * 4 + r;
        size_t col = nBase + wn + j * 16 + l15;
        store_c(C, row * (size_t)N + col, acc[i][j][r]);
      }
}

// ---------------------------------------------------------------------------
// RoPE in-place on q (heads 0..31) and k (heads 32..39) of qkv[2048][6144].
// ---------------------------------------------------------------------------
__global__ __launch_bounds__(256) void rope_kernel(__hip_bfloat16* __restrict__ qkv,
                                                   const float* __restrict__ fc) {
  int idx = blockIdx.x * 256 + threadIdx.x;  // 2048*40*64 total
  int d = idx & 63;
  int h = (idx >> 6) % 40;
  int s = idx / (40 * 64);
  size_t off = (size_t)s * 6144 + h * 128 + d * 2;
  float x0 = __bfloat162float(qkv[off]);
  float x1 = __bfloat162float(qkv[off + 1]);
  float c = fc[s * 128 + d * 2];
  float sn = fc[s * 128 + d * 2 + 1];
  qkv[off] = __float2bfloat16(x0 * c - x1 * sn);
  qkv[off + 1] = __float2bfloat16(x0 * sn + x1 * c);
}

// ---------------------------------------------------------------------------
// V transpose: vt[g*128+n][s] = qkv[s][5120 + g*128 + n].
// ---------------------------------------------------------------------------
__global__ __launch_bounds__(256) void transpose_v(const __hip_bfloat16* __restrict__ qkv,
                                                   __hip_bfloat16* __restrict__ vt) {
  __shared__ __hip_bfloat16 tile[32][33];
  int x = threadIdx.x & 31, y = threadIdx.x >> 5;
  int colBase = blockIdx.x * 32;
  int sBase = blockIdx.y * 32;
#pragma unroll
  for (int i = 0; i < 4; i++)
    tile[y + i * 8][x] = qkv[(size_t)(sBase + y + i * 8) * 6144 + 5120 + colBase + x];
  __syncthreads();
#pragma unroll
  for (int i = 0; i < 4; i++)
    vt[(size_t)(colBase + y + i * 8) * 2048 + sBase + x] = tile[x][y + i * 8];
}

// ---------------------------------------------------------------------------
// Flash attention, causal GQA. grid = (S/64, NH). 4 waves x 16 q-rows.
// K/Vt staged via global_load_lds with XOR-chunk swizzle on the SOURCE side
// (LDS dest must be lane-linear); fragment reads un-swizzle -> 2-way banks.
// P round-trips through LDS stride-72 (C-layout -> A-layout), barrier-guarded.
// ---------------------------------------------------------------------------
__global__ __launch_bounds__(256) void flash_attn(
    const __hip_bfloat16* __restrict__ qkv, const __hip_bfloat16* __restrict__ vt,
    __hip_bfloat16* __restrict__ o) {
  __shared__ __align__(16) __hip_bfloat16 Ks[64 * 128];
  __shared__ __align__(16) __hip_bfloat16 Vs[128 * 64];
  __shared__ __align__(16) __hip_bfloat16 Ps[4][16 * 72];
  const int tid = threadIdx.x;
  const int lane = tid & 63, wave = tid >> 6;
  const int l15 = lane & 15, quad = lane >> 4;
  const int h = blockIdx.y, g = h >> 2;  // GQA: kv head = h/4
  const int qBase = blockIdx.x * 64;
  const int qRow = qBase + wave * 16;

  bf16x8 qf[4];
  {
    const __hip_bfloat16* qp = qkv + (size_t)(qRow + l15) * 6144 + h * 128 + quad * 8;
#pragma unroll
    for (int d = 0; d < 4; d++) qf[d] = *(const bf16x8*)(qp + d * 32);
  }

  f32x4 acc_o[8] = {};
  float m_i[4], l_i[4];
#pragma unroll
  for (int r = 0; r < 4; r++) { m_i[r] = NEG_BIG; l_i[r] = 0.f; }

  const float scale = 0.08838834764831845f;  // 1/sqrt(128)
  const int nkt = blockIdx.x + 1;
  for (int kt = 0; kt < nkt; kt++) {
    const int kBase = kt * 64;
    // stage K tile [64 rows][16 slots]: slot chl holds global chunk chl^(row&15)
#pragma unroll
    for (int rnd = 0; rnd < 4; rnd++) {
      int ci = rnd * 256 + tid;
      int row = ci >> 4, chl = ci & 15;
      int chg = chl ^ (row & 15);
      ASYNC_CP16(qkv + (size_t)(kBase + row) * 6144 + 4096 + g * 128 + chg * 8, &Ks[ci * 8]);
    }
    // stage Vt tile [128 rows(n)][8 slots]: slot chl holds global chunk chl^(n&7)
#pragma unroll
    for (int rnd = 0; rnd < 4; rnd++) {
      int ci = rnd * 256 + tid;
      int n = ci >> 3, chl = ci & 7;
      int chg = chl ^ (n & 7);
      ASYNC_CP16(vt + (size_t)(g * 128 + n) * 2048 + kBase + chg * 8, &Vs[ci * 8]);
    }
    __syncthreads();

    // S = Q K^T : 4 d-steps x 4 k-col tiles (un-swizzle: slot = chunk ^ l15)
    f32x4 sc[4] = {};
#pragma unroll
    for (int d = 0; d < 4; d++) {
#pragma unroll
      for (int j = 0; j < 4; j++) {
        bf16x8 kb = *(const bf16x8*)&Ks[(j * 16 + l15) * 128 + ((d * 4 + quad) ^ l15) * 8];
        sc[j] = mfma_bf16(qf[d], kb, sc[j]);
      }
    }

    // scale + causal mask + online softmax (rows = quad*4+r over 16 lanes)
    float rowmax[4] = {NEG_BIG, NEG_BIG, NEG_BIG, NEG_BIG};
    float sv[4][4];
#pragma unroll
    for (int j = 0; j < 4; j++) {
      int kcol = kBase + j * 16 + l15;
#pragma unroll
      for (int r = 0; r < 4; r++) {
        float s = clampf(sc[j][r] * scale);  // tripwire: garbage can't become inf
        if (kcol > qRow + quad * 4 + r) s = NEG_BIG;
        sv[j][r] = s;
        rowmax[r] = fmaxf(rowmax[r], s);
      }
    }
#pragma unroll
    for (int off = 8; off; off >>= 1)
#pragma unroll
      for (int r = 0; r < 4; r++)
        rowmax[r] = fmaxf(rowmax[r], __shfl_xor(rowmax[r], off, 16));

    float alpha[4], rowsum[4];
#pragma unroll
    for (int r = 0; r < 4; r++) {
      float mnew = fmaxf(m_i[r], rowmax[r]);
      alpha[r] = __expf(m_i[r] - mnew);
      m_i[r] = mnew;
      rowsum[r] = 0.f;
    }
#pragma unroll
    for (int j = 0; j < 4; j++)
#pragma unroll
      for (int r = 0; r < 4; r++) {
        float p = __expf(sv[j][r] - m_i[r]);
        rowsum[r] += p;
        Ps[wave][(quad * 4 + r) * 72 + j * 16 + l15] = __float2bfloat16(p);
      }
#pragma unroll
    for (int off = 8; off; off >>= 1)
#pragma unroll
      for (int r = 0; r < 4; r++)
        rowsum[r] += __shfl_xor(rowsum[r], off, 16);
#pragma unroll
    for (int r = 0; r < 4; r++) l_i[r] = l_i[r] * alpha[r] + rowsum[r];

#pragma unroll
    for (int jt = 0; jt < 8; jt++)
#pragma unroll
      for (int r = 0; r < 4; r++) acc_o[jt][r] *= alpha[r];

    __syncthreads();  // P write (C-layout) -> P read (A-layout)

    // O += P V  (Vs un-swizzle: slot = chunk ^ (n&7))
#pragma unroll
    for (int kk = 0; kk < 2; kk++) {
      bf16x8 pa = *(const bf16x8*)&Ps[wave][l15 * 72 + kk * 32 + quad * 8];
#pragma unroll
      for (int jt = 0; jt < 8; jt++) {
        int n = jt * 16 + l15;
        bf16x8 vb = *(const bf16x8*)&Vs[n * 64 + (((kk * 4 + quad) ^ (n & 7))) * 8];
        acc_o[jt] = mfma_bf16(pa, vb, acc_o[jt]);
      }
    }
    __syncthreads();
  }

#pragma unroll
  for (int r = 0; r < 4; r++) {
    float inv = 1.f / l_i[r];
    size_t qr = qRow + quad * 4 + r;
#pragma unroll
    for (int jt = 0; jt < 8; jt++)
      o[qr * 4096 + h * 128 + jt * 16 + l15] = __float2bfloat16(clampf(acc_o[jt][r] * inv));
  }
}

// ---------------------------------------------------------------------------
extern "C" void kernel_launch(void* const* d_in, const int* in_sizes, int n_in,
                              void* d_out, int out_size, void* d_ws, size_t ws_size,
                              hipStream_t stream) {
  const float* x = (const float*)d_in[0];     // [2048][4096] fp32
  const float* fc = (const float*)d_in[1];    // [2048][64][2] fp32
  const float* wqkv = (const float*)d_in[2];  // [6144][4096] fp32
  const float* wo = (const float*)d_in[3];    // [4096][4096] fp32
  float* out = (float*)d_out;                 // [2048][4096] fp32

  char* ws = (char*)d_ws;
  __hip_bfloat16* qkv = (__hip_bfloat16*)ws;                        // 25,165,824 B
  __hip_bfloat16* vt  = (__hip_bfloat16*)(ws + 25165824);           //  4,194,304 B
  __hip_bfloat16* ob  = (__hip_bfloat16*)(ws + 29360128);           // 16,777,216 B
  // fast path extra buffers (end 46,137,344 proven available in round 4)
  __hip_bfloat16* xb  = (__hip_bfloat16*)(ws + 46137344);           // 16,777,216 B
  __hip_bfloat16* wb  = (__hip_bfloat16*)(ws + 62914560);           // 50,331,648 B -> end 113,246,208

  const bool fast = ws_size >= (size_t)113246208;  // constant across calls: graph-safe

  if (fast) {
    cvt_f32_bf16<<<dim3(4096), 256, 0, stream>>>(x, xb);        //  8.4M elems
    cvt_f32_bf16<<<dim3(12288), 256, 0, stream>>>(wqkv, wb);    // 25.2M elems
    gemm_nt_async<__hip_bfloat16>
        <<<dim3(48, 16), 256, 0, stream>>>(xb, wb, qkv, 2048, 6144, 4096);
  } else {
    gemm_nt<float, float, __hip_bfloat16>
        <<<dim3(48, 16), 256, 0, stream>>>(x, wqkv, qkv, 2048, 6144, 4096);
  }
  rope_kernel<<<dim3(20480), 256, 0, stream>>>(qkv, fc);
  transpose_v<<<dim3(32, 64), 256, 0, stream>>>(qkv, vt);
  flash_attn<<<dim3(32, 32), 256, 0, stream>>>(qkv, vt, ob);
  if (fast) {
    cvt_f32_bf16<<<dim3(8192), 256, 0, stream>>>(wo, wb);       // 16.8M elems (reuse wb)
    gemm_nt_async<float>
        <<<dim3(32, 16), 256, 0, stream>>>(ob, wb, out, 2048, 4096, 4096);
  } else {
    gemm_nt<__hip_bfloat16, float, float>
        <<<dim3(32, 16), 256, 0, stream>>>(ob, wo, out, 2048, 4096, 4096);
  }
}

// Round 6
// 553.177 us; speedup vs baseline: 1.4445x; 1.1461x over previous
//
#include <hip/hip_runtime.h>
#include <hip/hip_bf16.h>
#include <math.h>

// Problem constants: B=1, S=2048, DIM=4096, NH=32, NKV=8, HD=128
// qkv width = (32+2*8)*128 = 6144; q cols [0,4096), k cols [4096,5120), v cols [5120,6144)
//
// ROUND 6: (a) flash BQ=128 (K-frag reuse across 2 q-tiles, half the
// staging/barrier count, big-blocks-first dispatch); (b) RoPE + V-transpose
// fused into the qkv GEMM epilogue (shfl_xor pair exchange on fp32 accs).

typedef __attribute__((ext_vector_type(8))) __bf16 bf16x8;
typedef __attribute__((ext_vector_type(4))) __bf16 bf16x4;
typedef __attribute__((ext_vector_type(4))) float f32x4;

#define NEG_BIG (-1e30f)

#define ASYNC_CP16(gsrc, ldst)                                                            \
  __builtin_amdgcn_global_load_lds((const __attribute__((address_space(1))) void*)(gsrc), \
                                   (__attribute__((address_space(3))) void*)(ldst), 16, 0, 0)

__device__ __forceinline__ f32x4 mfma_bf16(bf16x8 a, bf16x8 b, f32x4 c) {
  return __builtin_amdgcn_mfma_f32_16x16x32_bf16(a, b, c, 0, 0, 0);
}

// fmaxf(NaN, a) = a on AMD (IEEE maxNum) -> clamp also converts NaN to -3e4.
__device__ __forceinline__ float clampf(float v) {
  return fminf(fmaxf(v, -30000.f), 30000.f);
}

__device__ __forceinline__ bf16x8 ldg8(const __hip_bfloat16* p) {
  return *(const bf16x8*)p;
}
__device__ __forceinline__ bf16x8 ldg8(const float* p) {
  f32x4 a = *(const f32x4*)p;
  f32x4 b = *(const f32x4*)(p + 4);
  bf16x8 r;
  r[0] = (__bf16)a[0]; r[1] = (__bf16)a[1]; r[2] = (__bf16)a[2]; r[3] = (__bf16)a[3];
  r[4] = (__bf16)b[0]; r[5] = (__bf16)b[1]; r[6] = (__bf16)b[2]; r[7] = (__bf16)b[3];
  return r;
}

__device__ __forceinline__ void store_c(float* C, size_t idx, float v) {
  C[idx] = clampf(v);
}
__device__ __forceinline__ void store_c(__hip_bfloat16* C, size_t idx, float v) {
  C[idx] = __float2bfloat16(clampf(v));
}

// ---------------------------------------------------------------------------
// fp32 -> bf16 bulk convert. 8 elems/thread.
// ---------------------------------------------------------------------------
__global__ __launch_bounds__(256) void cvt_f32_bf16(const float* __restrict__ src,
                                                    __hip_bfloat16* __restrict__ dst) {
  size_t i = ((size_t)blockIdx.x * 256 + threadIdx.x) * 8;
  *(bf16x8*)&dst[i] = ldg8(src + i);
}

// ---------------------------------------------------------------------------
// qkv GEMM with fused RoPE + V-transpose epilogue (fast path).
// qkv[s][c] = rope(x@wqkv^T) for c<5120 ; vt[c-5120][s] for c>=5120.
// M=2048, N=6144, K=4096 fixed. m97 structure, async staging.
// ---------------------------------------------------------------------------
__global__ __launch_bounds__(256) void gemm_qkv_rope(
    const __hip_bfloat16* __restrict__ A, const __hip_bfloat16* __restrict__ B,
    __hip_bfloat16* __restrict__ qkv, __hip_bfloat16* __restrict__ vt,
    const float* __restrict__ fc) {
  const int K = 4096;
  __shared__ __align__(16) __hip_bfloat16 As[128 * 32];
  __shared__ __align__(16) __hip_bfloat16 Bs[128 * 32];
  const int tid = threadIdx.x;
  const int lane = tid & 63, wave = tid >> 6;
  const int l15 = lane & 15, quad = lane >> 4;
  const int wm = (wave >> 1) * 64, wn = (wave & 1) * 64;
  const size_t mBase = (size_t)blockIdx.y * 128, nBase = (size_t)blockIdx.x * 128;

  const int ldRow = tid >> 2;
  const int ldCol = (tid & 3) * 8;
  const __hip_bfloat16* Ap = A + (mBase + ldRow) * (size_t)K + ldCol;
  const __hip_bfloat16* Bp = B + (nBase + ldRow) * (size_t)K + ldCol;

  f32x4 acc[4][4] = {};

  for (int k0 = 0; k0 < K; k0 += 32) {
    ASYNC_CP16(Ap, &As[tid * 8]);
    ASYNC_CP16(Ap + (size_t)64 * K, &As[2048 + tid * 8]);
    ASYNC_CP16(Bp, &Bs[tid * 8]);
    ASYNC_CP16(Bp + (size_t)64 * K, &Bs[2048 + tid * 8]);
    Ap += 32; Bp += 32;
    __syncthreads();
    bf16x8 af[4], bfr[4];
#pragma unroll
    for (int i = 0; i < 4; i++)
      af[i] = *(const bf16x8*)&As[(wm + i * 16 + l15) * 32 + quad * 8];
#pragma unroll
    for (int j = 0; j < 4; j++)
      bfr[j] = *(const bf16x8*)&Bs[(wn + j * 16 + l15) * 32 + quad * 8];
#pragma unroll
    for (int i = 0; i < 4; i++)
#pragma unroll
      for (int j = 0; j < 4; j++)
        acc[i][j] = mfma_bf16(af[i], bfr[j], acc[i][j]);
    __syncthreads();
  }

  // fused epilogue. c < 5120 is block-uniform (nBase multiple of 128).
#pragma unroll
  for (int i = 0; i < 4; i++)
#pragma unroll
    for (int j = 0; j < 4; j++) {
      size_t c = nBase + wn + j * 16 + l15;          // C/D: col=lane&15
      size_t srow0 = mBase + wm + i * 16 + quad * 4; // C/D: row=(lane>>4)*4+r
      if (c < 5120) {
        int di2 = (int)(c & 126);  // 2*(pair index within head)
#pragma unroll
        for (int r = 0; r < 4; r++) {
          float v = clampf(acc[i][j][r]);
          float vp = __shfl_xor(v, 1);  // pair-column partner (adjacent lane)
          size_t s = srow0 + r;
          float cs = fc[s * 128 + di2];
          float sn = fc[s * 128 + di2 + 1];
          float ov = ((c & 1) == 0) ? (v * cs - vp * sn) : (vp * sn + v * cs);
          qkv[s * 6144 + c] = __float2bfloat16(ov);
        }
      } else {
        bf16x4 pk;
#pragma unroll
        for (int r = 0; r < 4; r++) pk[r] = (__bf16)clampf(acc[i][j][r]);
        *(bf16x4*)&vt[(c - 5120) * 2048 + srow0] = pk;  // 8B packed, rows contiguous
      }
    }
}

// ---------------------------------------------------------------------------
// NT GEMM, m97 structure (fast path, out-proj): bf16 in, fp32/bf16 out.
// ---------------------------------------------------------------------------
template <typename TC>
__global__ __launch_bounds__(256) void gemm_nt_async(
    const __hip_bfloat16* __restrict__ A, const __hip_bfloat16* __restrict__ B,
    TC* __restrict__ C, int M, int N, int K) {
  __shared__ __align__(16) __hip_bfloat16 As[128 * 32];
  __shared__ __align__(16) __hip_bfloat16 Bs[128 * 32];
  const int tid = threadIdx.x;
  const int lane = tid & 63, wave = tid >> 6;
  const int l15 = lane & 15, quad = lane >> 4;
  const int wm = (wave >> 1) * 64, wn = (wave & 1) * 64;
  const size_t mBase = (size_t)blockIdx.y * 128, nBase = (size_t)blockIdx.x * 128;

  const int ldRow = tid >> 2;
  const int ldCol = (tid & 3) * 8;
  const __hip_bfloat16* Ap = A + (mBase + ldRow) * (size_t)K + ldCol;
  const __hip_bfloat16* Bp = B + (nBase + ldRow) * (size_t)K + ldCol;

  f32x4 acc[4][4] = {};

  for (int k0 = 0; k0 < K; k0 += 32) {
    ASYNC_CP16(Ap, &As[tid * 8]);
    ASYNC_CP16(Ap + (size_t)64 * K, &As[2048 + tid * 8]);
    ASYNC_CP16(Bp, &Bs[tid * 8]);
    ASYNC_CP16(Bp + (size_t)64 * K, &Bs[2048 + tid * 8]);
    Ap += 32; Bp += 32;
    __syncthreads();
    bf16x8 af[4], bfr[4];
#pragma unroll
    for (int i = 0; i < 4; i++)
      af[i] = *(const bf16x8*)&As[(wm + i * 16 + l15) * 32 + quad * 8];
#pragma unroll
    for (int j = 0; j < 4; j++)
      bfr[j] = *(const bf16x8*)&Bs[(wn + j * 16 + l15) * 32 + quad * 8];
#pragma unroll
    for (int i = 0; i < 4; i++)
#pragma unroll
      for (int j = 0; j < 4; j++)
        acc[i][j] = mfma_bf16(af[i], bfr[j], acc[i][j]);
    __syncthreads();
  }

#pragma unroll
  for (int i = 0; i < 4; i++)
#pragma unroll
    for (int j = 0; j < 4; j++)
#pragma unroll
      for (int r = 0; r < 4; r++) {
        size_t row = mBase + wm + i * 16 + quad * 4 + r;
        size_t col = nBase + wn + j * 16 + l15;
        store_c(C, row * (size_t)N + col, acc[i][j][r]);
      }
}

// ---------------------------------------------------------------------------
// Fallback path kernels (ws too small for bf16 weight buffers).
// ---------------------------------------------------------------------------
template <typename TA, typename TB, typename TC>
__global__ __launch_bounds__(256) void gemm_nt(
    const TA* __restrict__ A, const TB* __restrict__ B,
    TC* __restrict__ C, int M, int N, int K) {
  __shared__ __align__(16) __hip_bfloat16 As[128 * 32];
  __shared__ __align__(16) __hip_bfloat16 Bs[128 * 32];
  const int tid = threadIdx.x;
  const int lane = tid & 63, wave = tid >> 6;
  const int l15 = lane & 15, quad = lane >> 4;
  const int wm = (wave >> 1) * 64, wn = (wave & 1) * 64;
  const size_t mBase = (size_t)blockIdx.y * 128, nBase = (size_t)blockIdx.x * 128;
  const int ldRow = tid >> 2;
  const int ldCol = (tid & 3) * 8;
  const TA* Ap = A + (mBase + ldRow) * (size_t)K + ldCol;
  const TB* Bp = B + (nBase + ldRow) * (size_t)K + ldCol;
  f32x4 acc[4][4] = {};
  for (int k0 = 0; k0 < K; k0 += 32) {
    bf16x8 a0 = ldg8(Ap);
    bf16x8 a1 = ldg8(Ap + (size_t)64 * K);
    bf16x8 b0 = ldg8(Bp);
    bf16x8 b1 = ldg8(Bp + (size_t)64 * K);
    Ap += 32; Bp += 32;
    *(bf16x8*)&As[tid * 8] = a0;
    *(bf16x8*)&As[2048 + tid * 8] = a1;
    *(bf16x8*)&Bs[tid * 8] = b0;
    *(bf16x8*)&Bs[2048 + tid * 8] = b1;
    __syncthreads();
    bf16x8 af[4], bfr[4];
#pragma unroll
    for (int i = 0; i < 4; i++)
      af[i] = *(const bf16x8*)&As[(wm + i * 16 + l15) * 32 + quad * 8];
#pragma unroll
    for (int j = 0; j < 4; j++)
      bfr[j] = *(const bf16x8*)&Bs[(wn + j * 16 + l15) * 32 + quad * 8];
#pragma unroll
    for (int i = 0; i < 4; i++)
#pragma unroll
      for (int j = 0; j < 4; j++)
        acc[i][j] = mfma_bf16(af[i], bfr[j], acc[i][j]);
    __syncthreads();
  }
#pragma unroll
  for (int i = 0; i < 4; i++)
#pragma unroll
    for (int j = 0; j < 4; j++)
#pragma unroll
      for (int r = 0; r < 4; r++) {
        size_t row = mBase + wm + i * 16 + quad * 4 + r;
        size_t col = nBase + wn + j * 16 + l15;
        store_c(C, row * (size_t)N + col, acc[i][j][r]);
      }
}

__global__ __launch_bounds__(256) void rope_kernel(__hip_bfloat16* __restrict__ qkv,
                                                   const float* __restrict__ fc) {
  int idx = blockIdx.x * 256 + threadIdx.x;
  int d = idx & 63;
  int h = (idx >> 6) % 40;
  int s = idx / (40 * 64);
  size_t off = (size_t)s * 6144 + h * 128 + d * 2;
  float x0 = __bfloat162float(qkv[off]);
  float x1 = __bfloat162float(qkv[off + 1]);
  float c = fc[s * 128 + d * 2];
  float sn = fc[s * 128 + d * 2 + 1];
  qkv[off] = __float2bfloat16(x0 * c - x1 * sn);
  qkv[off + 1] = __float2bfloat16(x0 * sn + x1 * c);
}

__global__ __launch_bounds__(256) void transpose_v(const __hip_bfloat16* __restrict__ qkv,
                                                   __hip_bfloat16* __restrict__ vt) {
  __shared__ __hip_bfloat16 tile[32][33];
  int x = threadIdx.x & 31, y = threadIdx.x >> 5;
  int colBase = blockIdx.x * 32;
  int sBase = blockIdx.y * 32;
#pragma unroll
  for (int i = 0; i < 4; i++)
    tile[y + i * 8][x] = qkv[(size_t)(sBase + y + i * 8) * 6144 + 5120 + colBase + x];
  __syncthreads();
#pragma unroll
  for (int i = 0; i < 4; i++)
    vt[(size_t)(colBase + y + i * 8) * 2048 + sBase + x] = tile[x][y + i * 8];
}

// ---------------------------------------------------------------------------
// Flash attention, causal GQA. BQ=128: grid = (NH, S/128), qt reversed so
// diagonal-heavy blocks dispatch first. 4 waves x 32 q-rows (two 16-row
// A-frags -> K-fragment LDS reads reused 2x). K/Vt staged via global_load_lds
// with source-side XOR-chunk swizzle; Ps (16 rows/wave) reused for t=0,1
// (wave-private DS is in-order).
// ---------------------------------------------------------------------------
__global__ __launch_bounds__(256) void flash_attn(
    const __hip_bfloat16* __restrict__ qkv, const __hip_bfloat16* __restrict__ vt,
    __hip_bfloat16* __restrict__ o) {
  __shared__ __align__(16) __hip_bfloat16 Ks[64 * 128];
  __shared__ __align__(16) __hip_bfloat16 Vs[128 * 64];
  __shared__ __align__(16) __hip_bfloat16 Ps[4][16 * 72];
  const int tid = threadIdx.x;
  const int lane = tid & 63, wave = tid >> 6;
  const int l15 = lane & 15, quad = lane >> 4;
  const int h = blockIdx.x, g = h >> 2;        // GQA: kv head = h/4
  const int qt = 15 - blockIdx.y;              // big blocks first
  const int qBase = qt * 128;
  const int qRowW = qBase + wave * 32;         // this wave's 32 q-rows

  bf16x8 qf[2][4];
#pragma unroll
  for (int t = 0; t < 2; t++) {
    const __hip_bfloat16* qp =
        qkv + (size_t)(qRowW + t * 16 + l15) * 6144 + h * 128 + quad * 8;
#pragma unroll
    for (int d = 0; d < 4; d++) qf[t][d] = *(const bf16x8*)(qp + d * 32);
  }

  f32x4 acc_o[2][8] = {};
  float m_i[2][4], l_i[2][4];
#pragma unroll
  for (int t = 0; t < 2; t++)
#pragma unroll
    for (int r = 0; r < 4; r++) { m_i[t][r] = NEG_BIG; l_i[t][r] = 0.f; }

  const float scale = 0.08838834764831845f;  // 1/sqrt(128)
  const int nkt = 2 * qt + 2;
  for (int kt = 0; kt < nkt; kt++) {
    const int kBase = kt * 64;
    // stage K tile [64 rows][16 slots]: slot chl holds global chunk chl^(row&15)
#pragma unroll
    for (int rnd = 0; rnd < 4; rnd++) {
      int ci = rnd * 256 + tid;
      int row = ci >> 4, chl = ci & 15;
      int chg = chl ^ (row & 15);
      ASYNC_CP16(qkv + (size_t)(kBase + row) * 6144 + 4096 + g * 128 + chg * 8, &Ks[ci * 8]);
    }
    // stage Vt tile [128 rows(n)][8 slots]: slot chl holds global chunk chl^(n&7)
#pragma unroll
    for (int rnd = 0; rnd < 4; rnd++) {
      int ci = rnd * 256 + tid;
      int n = ci >> 3, chl = ci & 7;
      int chg = chl ^ (n & 7);
      ASYNC_CP16(vt + (size_t)(g * 128 + n) * 2048 + kBase + chg * 8, &Vs[ci * 8]);
    }
    __syncthreads();

    // S = Q K^T for both q-tiles; kb read once per (d,j), used twice
    f32x4 sc[2][4] = {};
#pragma unroll
    for (int d = 0; d < 4; d++) {
#pragma unroll
      for (int j = 0; j < 4; j++) {
        bf16x8 kb = *(const bf16x8*)&Ks[(j * 16 + l15) * 128 + ((d * 4 + quad) ^ l15) * 8];
        sc[0][j] = mfma_bf16(qf[0][d], kb, sc[0][j]);
        sc[1][j] = mfma_bf16(qf[1][d], kb, sc[1][j]);
      }
    }

#pragma unroll
    for (int t = 0; t < 2; t++) {
      const int qRowT = qRowW + t * 16;
      float rowmax[4] = {NEG_BIG, NEG_BIG, NEG_BIG, NEG_BIG};
      float sv[4][4];
#pragma unroll
      for (int j = 0; j < 4; j++) {
        int kcol = kBase + j * 16 + l15;
#pragma unroll
        for (int r = 0; r < 4; r++) {
          float s = clampf(sc[t][j][r] * scale);
          if (kcol > qRowT + quad * 4 + r) s = NEG_BIG;
          sv[j][r] = s;
          rowmax[r] = fmaxf(rowmax[r], s);
        }
      }
#pragma unroll
      for (int off = 8; off; off >>= 1)
#pragma unroll
        for (int r = 0; r < 4; r++)
          rowmax[r] = fmaxf(rowmax[r], __shfl_xor(rowmax[r], off, 16));

      float alpha[4], rowsum[4];
#pragma unroll
      for (int r = 0; r < 4; r++) {
        float mnew = fmaxf(m_i[t][r], rowmax[r]);
        alpha[r] = __expf(m_i[t][r] - mnew);
        m_i[t][r] = mnew;
        rowsum[r] = 0.f;
      }
#pragma unroll
      for (int j = 0; j < 4; j++)
#pragma unroll
        for (int r = 0; r < 4; r++) {
          float p = __expf(sv[j][r] - m_i[t][r]);
          rowsum[r] += p;
          Ps[wave][(quad * 4 + r) * 72 + j * 16 + l15] = __float2bfloat16(p);
        }
#pragma unroll
      for (int off = 8; off; off >>= 1)
#pragma unroll
        for (int r = 0; r < 4; r++)
          rowsum[r] += __shfl_xor(rowsum[r], off, 16);
#pragma unroll
      for (int r = 0; r < 4; r++) l_i[t][r] = l_i[t][r] * alpha[r] + rowsum[r];

#pragma unroll
      for (int jt = 0; jt < 8; jt++)
#pragma unroll
        for (int r = 0; r < 4; r++) acc_o[t][jt][r] *= alpha[r];

      // O += P V (wave-private Ps write->read: DS in-order, no barrier)
#pragma unroll
      for (int kk = 0; kk < 2; kk++) {
        bf16x8 pa = *(const bf16x8*)&Ps[wave][l15 * 72 + kk * 32 + quad * 8];
#pragma unroll
        for (int jt = 0; jt < 8; jt++) {
          int n = jt * 16 + l15;
          bf16x8 vb = *(const bf16x8*)&Vs[n * 64 + (((kk * 4 + quad) ^ (n & 7))) * 8];
          acc_o[t][jt] = mfma_bf16(pa, vb, acc_o[t][jt]);
        }
      }
    }
    __syncthreads();  // protect Ks/Vs from next tile's staging
  }

#pragma unroll
  for (int t = 0; t < 2; t++)
#pragma unroll
    for (int r = 0; r < 4; r++) {
      float inv = 1.f / l_i[t][r];
      size_t qr = qRowW + t * 16 + quad * 4 + r;
#pragma unroll
      for (int jt = 0; jt < 8; jt++)
        o[qr * 4096 + h * 128 + jt * 16 + l15] =
            __float2bfloat16(clampf(acc_o[t][jt][r] * inv));
    }
}

// ---------------------------------------------------------------------------
extern "C" void kernel_launch(void* const* d_in, const int* in_sizes, int n_in,
                              void* d_out, int out_size, void* d_ws, size_t ws_size,
                              hipStream_t stream) {
  const float* x = (const float*)d_in[0];     // [2048][4096] fp32
  const float* fc = (const float*)d_in[1];    // [2048][64][2] fp32
  const float* wqkv = (const float*)d_in[2];  // [6144][4096] fp32
  const float* wo = (const float*)d_in[3];    // [4096][4096] fp32
  float* out = (float*)d_out;                 // [2048][4096] fp32

  char* ws = (char*)d_ws;
  __hip_bfloat16* qkv = (__hip_bfloat16*)ws;                        // 25,165,824 B
  __hip_bfloat16* vt  = (__hip_bfloat16*)(ws + 25165824);           //  4,194,304 B
  __hip_bfloat16* ob  = (__hip_bfloat16*)(ws + 29360128);           // 16,777,216 B
  __hip_bfloat16* xb  = (__hip_bfloat16*)(ws + 46137344);           // 16,777,216 B
  __hip_bfloat16* wb  = (__hip_bfloat16*)(ws + 62914560);           // 50,331,648 B -> end 113,246,208

  const bool fast = ws_size >= (size_t)113246208;  // constant across calls: graph-safe

  if (fast) {
    cvt_f32_bf16<<<dim3(4096), 256, 0, stream>>>(x, xb);      //  8.4M elems
    cvt_f32_bf16<<<dim3(12288), 256, 0, stream>>>(wqkv, wb);  // 25.2M elems
    gemm_qkv_rope<<<dim3(48, 16), 256, 0, stream>>>(xb, wb, qkv, vt, fc);
  } else {
    gemm_nt<float, float, __hip_bfloat16>
        <<<dim3(48, 16), 256, 0, stream>>>(x, wqkv, qkv, 2048, 6144, 4096);
    rope_kernel<<<dim3(20480), 256, 0, stream>>>(qkv, fc);
    transpose_v<<<dim3(32, 64), 256, 0, stream>>>(qkv, vt);
  }
  flash_attn<<<dim3(32, 16), 256, 0, stream>>>(qkv, vt, ob);
  if (fast) {
    cvt_f32_bf16<<<dim3(8192), 256, 0, stream>>>(wo, wb);     // 16.8M elems (reuse wb)
    gemm_nt_async<float>
        <<<dim3(32, 16), 256, 0, stream>>>(ob, wb, out, 2048, 4096, 4096);
  } else {
    gemm_nt<__hip_bfloat16, float, float>
        <<<dim3(32, 16), 256, 0, stream>>>(ob, wo, out, 2048, 4096, 4096);
  }
}